// Round 5
// baseline (402.683 us; speedup 1.0000x reference)
//
#include <hip/hip_runtime.h>

#define B 2
#define E 1024
#define T 2048
#define H 16
#define DH 64

// log2(e) / sqrt(E)
#define SCALE2 0.0450842200277801f

typedef _Float16 f16x8 __attribute__((ext_vector_type(8)));
typedef float f32x4 __attribute__((ext_vector_type(4)));
typedef float f32x16 __attribute__((ext_vector_type(16)));
typedef unsigned short ushort8v __attribute__((ext_vector_type(8)));

__device__ __forceinline__ f32x4 mfma16(f16x8 a, f16x8 b, f32x4 c) {
  return __builtin_amdgcn_mfma_f32_16x16x32_f16(a, b, c, 0, 0, 0);
}
__device__ __forceinline__ f32x16 mfma32(f16x8 a, f16x8 b, f32x16 c) {
  return __builtin_amdgcn_mfma_f32_32x32x16_f16(a, b, c, 0, 0, 0);
}
__device__ __forceinline__ unsigned short f16u(float x) {
  _Float16 h = (_Float16)x;
  return __builtin_bit_cast(unsigned short, h);
}

// ---------------------------------------------------------------------------
// Weight prep: all 4 weights -> single fp16. grid (E*E/1024, 4)
// ---------------------------------------------------------------------------
__global__ __launch_bounds__(256) void prep_weights(
    const float* __restrict__ Wq, const float* __restrict__ Wk,
    const float* __restrict__ Wv, const float* __restrict__ Wo,
    unsigned short* __restrict__ WqB, unsigned short* __restrict__ WkB,
    unsigned short* __restrict__ WvB, unsigned short* __restrict__ WoB) {
  const int which = blockIdx.y;
  const int i = (blockIdx.x * 256 + threadIdx.x) * 4;
  const float* src = which == 0 ? Wq : which == 1 ? Wk : which == 2 ? Wv : Wo;
  unsigned short* dst = which == 0 ? WqB : which == 1 ? WkB : which == 2 ? WvB : WoB;
  float4 v = *(const float4*)&src[i];
  ((unsigned int*)&dst[i])[0] = f16u(v.x) | ((unsigned)f16u(v.y) << 16);
  ((unsigned int*)&dst[i])[1] = f16u(v.z) | ((unsigned)f16u(v.w) << 16);
}

// ---------------------------------------------------------------------------
// Transpose + convert: X [B][E][T] fp32 -> Xt [B][T][E] fp16 (q,k,v in one)
// ---------------------------------------------------------------------------
__global__ __launch_bounds__(256) void transpose_cvt(
    const float* __restrict__ q, const float* __restrict__ k,
    const float* __restrict__ v, unsigned short* __restrict__ XtQ,
    unsigned short* __restrict__ XtK, unsigned short* __restrict__ XtV) {
  __shared__ float Xs[32 * 36];
  const int z = blockIdx.z, which = z >> 1, b = z & 1;
  const float* X = which == 0 ? q : which == 1 ? k : v;
  unsigned short* O = which == 0 ? XtQ : which == 1 ? XtK : XtV;
  const int e0 = blockIdx.y * 32, t0 = blockIdx.x * 32;
  const int tid = threadIdx.x;
  const int r = tid >> 3, c = (tid & 7) * 4;
  *(float4*)&Xs[r * 36 + c] = *(const float4*)&X[((size_t)b * E + e0 + r) * T + t0 + c];
  __syncthreads();
  unsigned short h[4];
#pragma unroll
  for (int j = 0; j < 4; ++j) h[j] = f16u(Xs[(c + j) * 36 + r]);
  const size_t o = ((size_t)b * T + t0 + r) * E + e0 + c;
  ((unsigned int*)&O[o])[0] = h[0] | ((unsigned)h[1] << 16);
  ((unsigned int*)&O[o])[1] = h[2] | ((unsigned)h[3] << 16);
}

// ---------------------------------------------------------------------------
// Fused q/k/v projection, fp16.
// which 0: Q_eff = qmask*SCALE2*(W x + b)  (t-major [B][T][E])
// which 1: K_eff = kmask*(W x + b)         (t-major [B][T][E])
// which 2: vp    = vmask*(W x) + b         (d-major [B][E][T])
// ---------------------------------------------------------------------------
__global__ __launch_bounds__(256) void proj_qkv(
    const unsigned short* __restrict__ WqB, const unsigned short* __restrict__ WkB,
    const unsigned short* __restrict__ WvB, const unsigned short* __restrict__ XtQ,
    const unsigned short* __restrict__ XtK, const unsigned short* __restrict__ XtV,
    const float* __restrict__ bq, const float* __restrict__ bk,
    const float* __restrict__ bv, const float* __restrict__ qmask,
    const float* __restrict__ kmask, const float* __restrict__ vmask,
    unsigned short* __restrict__ qpT, unsigned short* __restrict__ kpT,
    unsigned short* __restrict__ vp) {
  __shared__ unsigned short Ah[128 * 72], Bs[128 * 72];
  const int b = blockIdx.z, my = blockIdx.y;
  const int which = my >> 3, o0 = (my & 7) * 128, t0 = blockIdx.x * 128;
  const unsigned short* W = which == 0 ? WqB : which == 1 ? WkB : WvB;
  const unsigned short* Xt = which == 0 ? XtQ : which == 1 ? XtK : XtV;
  const float* bias = which == 0 ? bq : which == 1 ? bk : bv;
  const float* mask = which == 0 ? qmask : which == 1 ? kmask : vmask;

  const int tid = threadIdx.x, wave = tid >> 6, lane = tid & 63;
  const int lg = lane & 15, quad = lane >> 4;
  const int wm = (wave & 1) * 64, wn = (wave >> 1) * 64;
  const int sr = tid >> 3, sc = (tid & 7) * 8;

  f32x4 acc[4][4];
#pragma unroll
  for (int i = 0; i < 4; ++i)
#pragma unroll
    for (int j = 0; j < 4; ++j) acc[i][j] = (f32x4){0.f, 0.f, 0.f, 0.f};

  for (int k0 = 0; k0 < E; k0 += 64) {
    ushort8v ra[4], rb[4];
#pragma unroll
    for (int p = 0; p < 4; ++p) {
      ra[p] = *(const ushort8v*)&W[(size_t)(o0 + p * 32 + sr) * E + k0 + sc];
      rb[p] = *(const ushort8v*)&Xt[((size_t)b * T + t0 + p * 32 + sr) * E + k0 + sc];
    }
    __syncthreads();
#pragma unroll
    for (int p = 0; p < 4; ++p) {
      *(ushort8v*)&Ah[(p * 32 + sr) * 72 + sc] = ra[p];
      *(ushort8v*)&Bs[(p * 32 + sr) * 72 + sc] = rb[p];
    }
    __syncthreads();
    f16x8 af[4][2];
#pragma unroll
    for (int mt = 0; mt < 4; ++mt) {
      af[mt][0] = *(const f16x8*)&Ah[(wm + mt * 16 + lg) * 72 + quad * 8];
      af[mt][1] = *(const f16x8*)&Ah[(wm + mt * 16 + lg) * 72 + 32 + quad * 8];
    }
#pragma unroll
    for (int nt = 0; nt < 4; ++nt) {
      f16x8 b0 = *(const f16x8*)&Bs[(wn + nt * 16 + lg) * 72 + quad * 8];
      f16x8 b1 = *(const f16x8*)&Bs[(wn + nt * 16 + lg) * 72 + 32 + quad * 8];
#pragma unroll
      for (int mt = 0; mt < 4; ++mt) {
        f32x4 c = acc[mt][nt];
        c = mfma16(af[mt][0], b0, c);
        c = mfma16(af[mt][1], b1, c);
        acc[mt][nt] = c;
      }
    }
  }
#pragma unroll
  for (int nt = 0; nt < 4; ++nt) {
    const int tcol = t0 + wn + nt * 16 + lg;
    const float mv = mask[b * T + tcol];
#pragma unroll
    for (int mt = 0; mt < 4; ++mt) {
      const int oF = o0 + wm + mt * 16 + quad * 4;
      float v4[4];
      if (which == 0) {
        const float s = mv * SCALE2;
#pragma unroll
        for (int r = 0; r < 4; ++r) v4[r] = (acc[mt][nt][r] + bias[oF + r]) * s;
      } else if (which == 1) {
#pragma unroll
        for (int r = 0; r < 4; ++r) v4[r] = (acc[mt][nt][r] + bias[oF + r]) * mv;
      } else {
#pragma unroll
        for (int r = 0; r < 4; ++r) v4[r] = acc[mt][nt][r] * mv + bias[oF + r];
      }
      if (which <= 1) {
        unsigned short* O = which == 0 ? qpT : kpT;
        const size_t o = ((size_t)b * T + tcol) * E + oF;
        ((unsigned int*)&O[o])[0] = f16u(v4[0]) | ((unsigned)f16u(v4[1]) << 16);
        ((unsigned int*)&O[o])[1] = f16u(v4[2]) | ((unsigned)f16u(v4[3]) << 16);
      } else {
#pragma unroll
        for (int r = 0; r < 4; ++r)
          vp[((size_t)b * E + oF + r) * T + tcol] = f16u(v4[r]);
      }
    }
  }
}

// ---------------------------------------------------------------------------
// Stats: lLog[q] = -log2( sum_k exp2(S_eff[q,k]) ). LDS-free, barrier-free.
// 32x32x16 MFMA; Q-frags resident per wave (32 q-rows), K-frags direct-global
// with 1-deep prefetch. Grid (T/128, B*H).
// ---------------------------------------------------------------------------
__global__ __launch_bounds__(256) void attn_stats(
    const unsigned short* __restrict__ qpT, const unsigned short* __restrict__ kpT,
    float* __restrict__ lLogOut) {
  const int bh = blockIdx.y, b = bh >> 4, h = bh & 15;
  const int q0 = blockIdx.x * 128;
  const int tid = threadIdx.x, wave = tid >> 6, lane = tid & 63;
  const int ln = lane & 31, half = lane >> 5;

  const f16x8* qrow =
      (const f16x8*)(qpT + ((size_t)b * T + q0 + wave * 32 + ln) * E + h * DH);
  f16x8 aq[4];
#pragma unroll
  for (int s = 0; s < 4; ++s) aq[s] = qrow[s * 2 + half];

  float lacc[16];
#pragma unroll
  for (int r = 0; r < 16; ++r) lacc[r] = 0.f;

  f16x8 bkr[2][4];
#pragma unroll
  for (int nt = 0; nt < 2; ++nt) {
    const f16x8* kr = (const f16x8*)(kpT + ((size_t)b * T + nt * 32 + ln) * E + h * DH);
#pragma unroll
    for (int s = 0; s < 4; ++s) bkr[nt][s] = kr[s * 2 + half];
  }
  for (int kt = 0; kt < T; kt += 64) {
    const int kn = (kt + 64) & (T - 1);
    f16x8 nb[2][4];
#pragma unroll
    for (int nt = 0; nt < 2; ++nt) {
      const f16x8* kr =
          (const f16x8*)(kpT + ((size_t)b * T + kn + nt * 32 + ln) * E + h * DH);
#pragma unroll
      for (int s = 0; s < 4; ++s) nb[nt][s] = kr[s * 2 + half];
    }
    f32x16 S0 = {}, S1 = {};
#pragma unroll
    for (int s = 0; s < 4; ++s) {
      S0 = mfma32(aq[s], bkr[0][s], S0);
      S1 = mfma32(aq[s], bkr[1][s], S1);
    }
#pragma unroll
    for (int r = 0; r < 16; ++r) lacc[r] += exp2f(S0[r]) + exp2f(S1[r]);
#pragma unroll
    for (int nt = 0; nt < 2; ++nt)
#pragma unroll
      for (int s = 0; s < 4; ++s) bkr[nt][s] = nb[nt][s];
  }
#pragma unroll
  for (int off = 1; off < 32; off <<= 1)
#pragma unroll
    for (int r = 0; r < 16; ++r) lacc[r] += __shfl_xor(lacc[r], off, 64);
  if (ln == 0) {
#pragma unroll
    for (int t = 0; t < 4; ++t) {
      f32x4 o;
#pragma unroll
      for (int j = 0; j < 4; ++j) o[j] = -__log2f(lacc[t * 4 + j]);
      *(f32x4*)&lLogOut[(size_t)bh * T + q0 + wave * 32 + t * 8 + half * 4] = o;
    }
  }
}

// ---------------------------------------------------------------------------
// Apply: ao[d,k] = sum_q V[d,q] * exp2(S_eff[q,k] + lLog[q]).
// Block: 64 k-cols, 4 waves = (2 k-tiles) x (2 q-halves); 128 q rows/iter.
// All operand fragments direct-global (16B contiguous per lane, L1-shared);
// P transpose in wave-private LDS -> ZERO barriers inside the q-loop.
// q-half partials merged once in the epilogue via LDS. Output fp16 t-major.
// ---------------------------------------------------------------------------
__global__ __launch_bounds__(256, 4) void attn_apply(
    const unsigned short* __restrict__ qpT, const unsigned short* __restrict__ kpT,
    const unsigned short* __restrict__ vp, const float* __restrict__ lLog,
    unsigned short* __restrict__ ao) {
  __shared__ unsigned short Pt[2][64 * 68];  // [qh][k-row][q'] fp16
  const int bh = blockIdx.y, b = bh >> 4, h = bh & 15;
  const int kblk = blockIdx.x * 64;
  const int tid = threadIdx.x, wave = tid >> 6, lane = tid & 63;
  const int ln = lane & 31, half = lane >> 5;
  const int kt = wave & 1, qh = wave >> 1;

  // resident K_eff B-frags for this wave's 32 k-cols
  const f16x8* krow =
      (const f16x8*)(kpT + ((size_t)b * T + kblk + kt * 32 + ln) * E + h * DH);
  f16x8 bkk[4];
#pragma unroll
  for (int s = 0; s < 4; ++s) bkk[s] = krow[s * 2 + half];

  f32x16 acc0 = {}, acc1 = {};

  for (int qt = 0; qt < T; qt += 128) {
    const int qbase = qt + qh * 64;
    // Q A-frags (2 m-tiles of 32 q)
    f16x8 aq[2][4];
#pragma unroll
    for (int mt = 0; mt < 2; ++mt) {
      const f16x8* qr =
          (const f16x8*)(qpT + ((size_t)b * T + qbase + mt * 32 + ln) * E + h * DH);
#pragma unroll
      for (int s = 0; s < 4; ++s) aq[mt][s] = qr[s * 2 + half];
    }
    // lLog in C-layout rows
    f32x4 ll[2][4];
#pragma unroll
    for (int mt = 0; mt < 2; ++mt)
#pragma unroll
      for (int t = 0; t < 4; ++t)
        ll[mt][t] = *(const f32x4*)&lLog[(size_t)bh * T + qbase + mt * 32 + t * 8 + half * 4];
    // QK^T
    f32x16 S0 = {}, S1 = {};
#pragma unroll
    for (int s = 0; s < 4; ++s) {
      S0 = mfma32(aq[0][s], bkk[s], S0);
      S1 = mfma32(aq[1][s], bkk[s], S1);
    }
    // P = exp2(S + lLog) -> Pt (wave-private rows = own k-cols)
#pragma unroll
    for (int mt = 0; mt < 2; ++mt) {
      const f32x16& S = mt ? S1 : S0;
#pragma unroll
      for (int t = 0; t < 4; ++t) {
        unsigned short p0 = f16u(exp2f(S[t * 4 + 0] + ll[mt][t][0]));
        unsigned short p1 = f16u(exp2f(S[t * 4 + 1] + ll[mt][t][1]));
        unsigned short p2 = f16u(exp2f(S[t * 4 + 2] + ll[mt][t][2]));
        unsigned short p3 = f16u(exp2f(S[t * 4 + 3] + ll[mt][t][3]));
        uint2 w;
        w.x = p0 | ((unsigned)p1 << 16);
        w.y = p2 | ((unsigned)p3 << 16);
        *(uint2*)&Pt[qh][(kt * 32 + ln) * 68 + mt * 32 + t * 8 + half * 4] = w;
      }
    }
    // V A-frags (2 d-tiles, own q-half) + PV
#pragma unroll
    for (int s = 0; s < 4; ++s) {
      f16x8 av0 = *(const f16x8*)(vp + ((size_t)b * E + h * DH + ln) * T + qbase +
                                  s * 16 + half * 8);
      f16x8 av1 = *(const f16x8*)(vp + ((size_t)b * E + h * DH + 32 + ln) * T + qbase +
                                  s * 16 + half * 8);
      f16x8 pb = *(const f16x8*)&Pt[qh][(kt * 32 + ln) * 68 + s * 16 + half * 8];
      acc0 = mfma32(av0, pb, acc0);
      acc1 = mfma32(av1, pb, acc1);
    }
  }

  // merge q-half partials: waves qh=1 stash to LDS, waves qh=0 add + store
  float* st = (float*)&Pt[0][0];
  __syncthreads();
  if (qh == 1) {
#pragma unroll
    for (int i = 0; i < 16; ++i) {
      st[i * 130 + kt * 65 + lane] = acc0[i];
      st[(16 + i) * 130 + kt * 65 + lane] = acc1[i];
    }
  }
  __syncthreads();
  if (qh == 0) {
#pragma unroll
    for (int i = 0; i < 16; ++i) {
      acc0[i] += st[i * 130 + kt * 65 + lane];
      acc1[i] += st[(16 + i) * 130 + kt * 65 + lane];
    }
    const int kcol = kblk + kt * 32 + ln;
    const size_t obase = ((size_t)b * T + kcol) * E + h * DH;
#pragma unroll
    for (int dt = 0; dt < 2; ++dt) {
#pragma unroll
      for (int t = 0; t < 4; ++t) {
        const float* a = dt ? (const float*)&acc1 : (const float*)&acc0;
        uint2 w;
        w.x = f16u(a[t * 4 + 0]) | ((unsigned)f16u(a[t * 4 + 1]) << 16);
        w.y = f16u(a[t * 4 + 2]) | ((unsigned)f16u(a[t * 4 + 3]) << 16);
        *(uint2*)&ao[obase + dt * 32 + t * 8 + half * 4] = w;
      }
    }
  }
}

// ---------------------------------------------------------------------------
// Final projection, single fp16 mfma32: out = km[t]*(Wo . ao) + bo, fp32.
// Tile 64(o) x 128(t), BK=64; 4 waves over t; grid (T/128, E/64, B) = 512.
// ---------------------------------------------------------------------------
__global__ __launch_bounds__(256) void proj_final(
    const unsigned short* __restrict__ WoB, const unsigned short* __restrict__ ao,
    const float* __restrict__ bo, const float* __restrict__ kmask,
    float* __restrict__ out) {
  __shared__ unsigned short As[64 * 68], Bs[128 * 68];
  const int b = blockIdx.z, o0 = blockIdx.y * 64, t0 = blockIdx.x * 128;
  const int tid = threadIdx.x, wave = tid >> 6, lane = tid & 63;
  const int ln = lane & 31, half = lane >> 5;
  const int wn = wave * 32;
  const int ar = tid >> 2, ac = (tid & 3) * 16;
  const int br = tid >> 1, bc = (tid & 1) * 32;

  f32x16 acc0 = {}, acc1 = {};

  for (int k0 = 0; k0 < E; k0 += 64) {
    ushort8v a0 = *(const ushort8v*)&WoB[(size_t)(o0 + ar) * E + k0 + ac];
    ushort8v a1 = *(const ushort8v*)&WoB[(size_t)(o0 + ar) * E + k0 + ac + 8];
    ushort8v b0 = *(const ushort8v*)&ao[((size_t)b * T + t0 + br) * E + k0 + bc];
    ushort8v b1 = *(const ushort8v*)&ao[((size_t)b * T + t0 + br) * E + k0 + bc + 8];
    ushort8v b2 = *(const ushort8v*)&ao[((size_t)b * T + t0 + br) * E + k0 + bc + 16];
    ushort8v b3 = *(const ushort8v*)&ao[((size_t)b * T + t0 + br) * E + k0 + bc + 24];
    __syncthreads();
    *(ushort8v*)&As[ar * 68 + ac] = a0;
    *(ushort8v*)&As[ar * 68 + ac + 8] = a1;
    *(ushort8v*)&Bs[br * 68 + bc] = b0;
    *(ushort8v*)&Bs[br * 68 + bc + 8] = b1;
    *(ushort8v*)&Bs[br * 68 + bc + 16] = b2;
    *(ushort8v*)&Bs[br * 68 + bc + 24] = b3;
    __syncthreads();
#pragma unroll
    for (int s = 0; s < 4; ++s) {
      f16x8 af0 = *(const f16x8*)&As[ln * 68 + s * 16 + half * 8];
      f16x8 af1 = *(const f16x8*)&As[(32 + ln) * 68 + s * 16 + half * 8];
      f16x8 bf = *(const f16x8*)&Bs[(wn + ln) * 68 + s * 16 + half * 8];
      acc0 = mfma32(af0, bf, acc0);
      acc1 = mfma32(af1, bf, acc1);
    }
  }
  const int tcol = t0 + wn + ln;
  const float mv = kmask[b * T + tcol];
#pragma unroll
  for (int dt = 0; dt < 2; ++dt) {
    const float* a = dt ? (const float*)&acc1 : (const float*)&acc0;
#pragma unroll
    for (int t = 0; t < 4; ++t)
#pragma unroll
      for (int j = 0; j < 4; ++j) {
        const int e = o0 + dt * 32 + t * 8 + half * 4 + j;
        out[((size_t)b * E + e) * T + tcol] = a[t * 4 + j] * mv + bo[e];
      }
  }
}

extern "C" void kernel_launch(void* const* d_in, const int* in_sizes, int n_in,
                              void* d_out, int out_size, void* d_ws, size_t ws_size,
                              hipStream_t stream) {
  const float* q = (const float*)d_in[0];
  const float* k = (const float*)d_in[1];
  const float* v = (const float*)d_in[2];
  const float* qmask = (const float*)d_in[3];
  const float* kmask = (const float*)d_in[4];
  const float* vmask = (const float*)d_in[5];
  const float* Wq = (const float*)d_in[6];
  const float* bq = (const float*)d_in[7];
  const float* Wk = (const float*)d_in[8];
  const float* bk = (const float*)d_in[9];
  const float* Wv = (const float*)d_in[10];
  const float* bv = (const float*)d_in[11];
  const float* Wo = (const float*)d_in[12];
  const float* bo = (const float*)d_in[13];

  char* w = (char*)d_ws;
  const size_t WB = (size_t)E * E * sizeof(unsigned short);      // 2 MB
  const size_t TB = (size_t)B * T * E * sizeof(unsigned short);  // 8 MB
  unsigned short* WqB = (unsigned short*)(w + 0 * WB);
  unsigned short* WkB = (unsigned short*)(w + 1 * WB);
  unsigned short* WvB = (unsigned short*)(w + 2 * WB);
  unsigned short* WoB = (unsigned short*)(w + 3 * WB);
  size_t off = 4 * WB;
  unsigned short* XtQ = (unsigned short*)(w + off); off += TB;
  unsigned short* XtK = (unsigned short*)(w + off); off += TB;
  unsigned short* XtV = (unsigned short*)(w + off); off += TB;
  unsigned short* qpT = (unsigned short*)(w + off); off += TB;
  unsigned short* kpT = (unsigned short*)(w + off); off += TB;
  unsigned short* vp  = (unsigned short*)(w + off); off += TB;
  float* lLog = (float*)(w + off); off += (size_t)B * H * T * sizeof(float);
  unsigned short* ao = XtQ;  // dead after proj_qkv

  dim3 bl(256);
  prep_weights<<<dim3((E * E) / 1024, 4), bl, 0, stream>>>(
      Wq, Wk, Wv, Wo, WqB, WkB, WvB, WoB);
  transpose_cvt<<<dim3(T / 32, E / 32, 3 * B), bl, 0, stream>>>(
      q, k, v, XtQ, XtK, XtV);
  proj_qkv<<<dim3(T / 128, 24, B), bl, 0, stream>>>(
      WqB, WkB, WvB, XtQ, XtK, XtV, bq, bk, bv, qmask, kmask, vmask, qpT, kpT, vp);
  attn_stats<<<dim3(T / 128, B * H), bl, 0, stream>>>(qpT, kpT, lLog);
  attn_apply<<<dim3(T / 64, B * H), bl, 0, stream>>>(qpT, kpT, vp, lLog, ao);
  proj_final<<<dim3(T / 128, E / 64, B), bl, 0, stream>>>(
      WoB, ao, bo, kmask, (float*)d_out);
}

// Round 6
// 321.035 us; speedup vs baseline: 1.2543x; 1.2543x over previous
//
#include <hip/hip_runtime.h>

#define B 2
#define E 1024
#define T 2048
#define H 16
#define DH 64

// log2(e) / sqrt(E)
#define SCALE2 0.0450842200277801f

typedef _Float16 f16x8 __attribute__((ext_vector_type(8)));
typedef float f32x4 __attribute__((ext_vector_type(4)));
typedef float f32x16 __attribute__((ext_vector_type(16)));
typedef unsigned short ushort8v __attribute__((ext_vector_type(8)));
typedef unsigned int uint4v __attribute__((ext_vector_type(4)));

__device__ __forceinline__ f32x4 mfma16(f16x8 a, f16x8 b, f32x4 c) {
  return __builtin_amdgcn_mfma_f32_16x16x32_f16(a, b, c, 0, 0, 0);
}
__device__ __forceinline__ f32x16 mfma32(f16x8 a, f16x8 b, f32x16 c) {
  return __builtin_amdgcn_mfma_f32_32x32x16_f16(a, b, c, 0, 0, 0);
}
__device__ __forceinline__ unsigned short f16u(float x) {
  _Float16 h = (_Float16)x;
  return __builtin_bit_cast(unsigned short, h);
}

// ---------------------------------------------------------------------------
// Weight prep: all 4 weights -> single fp16. grid (E*E/1024, 4)
// ---------------------------------------------------------------------------
__global__ __launch_bounds__(256) void prep_weights(
    const float* __restrict__ Wq, const float* __restrict__ Wk,
    const float* __restrict__ Wv, const float* __restrict__ Wo,
    unsigned short* __restrict__ WqB, unsigned short* __restrict__ WkB,
    unsigned short* __restrict__ WvB, unsigned short* __restrict__ WoB) {
  const int which = blockIdx.y;
  const int i = (blockIdx.x * 256 + threadIdx.x) * 4;
  const float* src = which == 0 ? Wq : which == 1 ? Wk : which == 2 ? Wv : Wo;
  unsigned short* dst = which == 0 ? WqB : which == 1 ? WkB : which == 2 ? WvB : WoB;
  float4 v = *(const float4*)&src[i];
  ((unsigned int*)&dst[i])[0] = f16u(v.x) | ((unsigned)f16u(v.y) << 16);
  ((unsigned int*)&dst[i])[1] = f16u(v.z) | ((unsigned)f16u(v.w) << 16);
}

// ---------------------------------------------------------------------------
// Transpose + convert: X [B][E][T] fp32 -> Xt [B][T][E] fp16 (q,k,v in one)
// ---------------------------------------------------------------------------
__global__ __launch_bounds__(256) void transpose_cvt(
    const float* __restrict__ q, const float* __restrict__ k,
    const float* __restrict__ v, unsigned short* __restrict__ XtQ,
    unsigned short* __restrict__ XtK, unsigned short* __restrict__ XtV) {
  __shared__ float Xs[32 * 36];
  const int z = blockIdx.z, which = z >> 1, b = z & 1;
  const float* X = which == 0 ? q : which == 1 ? k : v;
  unsigned short* O = which == 0 ? XtQ : which == 1 ? XtK : XtV;
  const int e0 = blockIdx.y * 32, t0 = blockIdx.x * 32;
  const int tid = threadIdx.x;
  const int r = tid >> 3, c = (tid & 7) * 4;
  *(float4*)&Xs[r * 36 + c] = *(const float4*)&X[((size_t)b * E + e0 + r) * T + t0 + c];
  __syncthreads();
  unsigned short h[4];
#pragma unroll
  for (int j = 0; j < 4; ++j) h[j] = f16u(Xs[(c + j) * 36 + r]);
  const size_t o = ((size_t)b * T + t0 + r) * E + e0 + c;
  ((unsigned int*)&O[o])[0] = h[0] | ((unsigned)h[1] << 16);
  ((unsigned int*)&O[o])[1] = h[2] | ((unsigned)h[3] << 16);
}

// ---------------------------------------------------------------------------
// Fused q/k/v projection, fp16.
// which 0: Q_eff = qmask*SCALE2*(W x + b) -> FRAGMENT-MAJOR qp2
// which 1: K_eff = kmask*(W x + b)        -> FRAGMENT-MAJOR kp2
// which 2: vp    = vmask*(W x) + b        -> d-major [B][E][T] (repacked later)
// Fragment-major layout: [bh][T/32][4 s][32 lane][2 half][8] fp16, where the
// fragment element j maps to d = s*16 + half*8 + j and lane = t (mod 32).
// ---------------------------------------------------------------------------
__global__ __launch_bounds__(256) void proj_qkv(
    const unsigned short* __restrict__ WqB, const unsigned short* __restrict__ WkB,
    const unsigned short* __restrict__ WvB, const unsigned short* __restrict__ XtQ,
    const unsigned short* __restrict__ XtK, const unsigned short* __restrict__ XtV,
    const float* __restrict__ bq, const float* __restrict__ bk,
    const float* __restrict__ bv, const float* __restrict__ qmask,
    const float* __restrict__ kmask, const float* __restrict__ vmask,
    unsigned short* __restrict__ qp2, unsigned short* __restrict__ kp2,
    unsigned short* __restrict__ vp) {
  __shared__ unsigned short Ah[128 * 72], Bs[128 * 72];
  const int b = blockIdx.z, my = blockIdx.y;
  const int which = my >> 3, o0 = (my & 7) * 128, t0 = blockIdx.x * 128;
  const unsigned short* W = which == 0 ? WqB : which == 1 ? WkB : WvB;
  const unsigned short* Xt = which == 0 ? XtQ : which == 1 ? XtK : XtV;
  const float* bias = which == 0 ? bq : which == 1 ? bk : bv;
  const float* mask = which == 0 ? qmask : which == 1 ? kmask : vmask;

  const int tid = threadIdx.x, wave = tid >> 6, lane = tid & 63;
  const int lg = lane & 15, quad = lane >> 4;
  const int wm = (wave & 1) * 64, wn = (wave >> 1) * 64;
  const int sr = tid >> 3, sc = (tid & 7) * 8;

  f32x4 acc[4][4];
#pragma unroll
  for (int i = 0; i < 4; ++i)
#pragma unroll
    for (int j = 0; j < 4; ++j) acc[i][j] = (f32x4){0.f, 0.f, 0.f, 0.f};

  for (int k0 = 0; k0 < E; k0 += 64) {
    ushort8v ra[4], rb[4];
#pragma unroll
    for (int p = 0; p < 4; ++p) {
      ra[p] = *(const ushort8v*)&W[(size_t)(o0 + p * 32 + sr) * E + k0 + sc];
      rb[p] = *(const ushort8v*)&Xt[((size_t)b * T + t0 + p * 32 + sr) * E + k0 + sc];
    }
    __syncthreads();
#pragma unroll
    for (int p = 0; p < 4; ++p) {
      *(ushort8v*)&Ah[(p * 32 + sr) * 72 + sc] = ra[p];
      *(ushort8v*)&Bs[(p * 32 + sr) * 72 + sc] = rb[p];
    }
    __syncthreads();
    f16x8 af[4][2];
#pragma unroll
    for (int mt = 0; mt < 4; ++mt) {
      af[mt][0] = *(const f16x8*)&Ah[(wm + mt * 16 + lg) * 72 + quad * 8];
      af[mt][1] = *(const f16x8*)&Ah[(wm + mt * 16 + lg) * 72 + 32 + quad * 8];
    }
#pragma unroll
    for (int nt = 0; nt < 4; ++nt) {
      f16x8 b0 = *(const f16x8*)&Bs[(wn + nt * 16 + lg) * 72 + quad * 8];
      f16x8 b1 = *(const f16x8*)&Bs[(wn + nt * 16 + lg) * 72 + 32 + quad * 8];
#pragma unroll
      for (int mt = 0; mt < 4; ++mt) {
        f32x4 c = acc[mt][nt];
        c = mfma16(af[mt][0], b0, c);
        c = mfma16(af[mt][1], b1, c);
        acc[mt][nt] = c;
      }
    }
  }
#pragma unroll
  for (int nt = 0; nt < 4; ++nt) {
    const int tcol = t0 + wn + nt * 16 + lg;
    const float mv = mask[b * T + tcol];
#pragma unroll
    for (int mt = 0; mt < 4; ++mt) {
      const int oF = o0 + wm + mt * 16 + quad * 4;
      float v4[4];
      if (which == 0) {
        const float s = mv * SCALE2;
#pragma unroll
        for (int r = 0; r < 4; ++r) v4[r] = (acc[mt][nt][r] + bias[oF + r]) * s;
      } else if (which == 1) {
#pragma unroll
        for (int r = 0; r < 4; ++r) v4[r] = (acc[mt][nt][r] + bias[oF + r]) * mv;
      } else {
#pragma unroll
        for (int r = 0; r < 4; ++r) v4[r] = acc[mt][nt][r] * mv + bias[oF + r];
      }
      if (which <= 1) {
        unsigned short* O = which == 0 ? qp2 : kp2;
        const int head = (o0 + wm) >> 6;
        const int bh2 = b * H + head;
        const size_t idx8 =
            (((size_t)(bh2 * (T / 32) + (tcol >> 5)) * 4 + mt) * 32 + (tcol & 31)) * 2 +
            (quad >> 1);
        unsigned int* dst = (unsigned int*)(O + idx8 * 8 + (quad & 1) * 4);
        dst[0] = f16u(v4[0]) | ((unsigned)f16u(v4[1]) << 16);
        dst[1] = f16u(v4[2]) | ((unsigned)f16u(v4[3]) << 16);
      } else {
#pragma unroll
        for (int r = 0; r < 4; ++r)
          vp[((size_t)b * E + oF + r) * T + tcol] = f16u(v4[r]);
      }
    }
  }
}

// ---------------------------------------------------------------------------
// Repack V: vp d-major [B][E][T] -> vp2 A-fragment-major
// [bh][T/16][2 dt][32 lane(d)][2 half][8] fp16 (element j -> q = half*8+j).
// grid (T/128, H, B), block 256.
// ---------------------------------------------------------------------------
__global__ __launch_bounds__(256) void repack_v(
    const unsigned short* __restrict__ vp, unsigned short* __restrict__ vp2) {
  __shared__ unsigned short Ls[64 * 136];
  const int q0 = blockIdx.x * 128, hh = blockIdx.y, b = blockIdx.z;
  const int bh = b * H + hh;
  const int tid = threadIdx.x;
  // stage 64 d x 128 q, coalesced
#pragma unroll
  for (int w = 0; w < 2; ++w) {
    const int d = w * 32 + (tid >> 3);
    const int c = (tid & 7) * 16;
    const unsigned short* src = vp + ((size_t)b * E + hh * DH + d) * T + q0 + c;
    *(ushort8v*)&Ls[d * 136 + c] = *(const ushort8v*)src;
    *(ushort8v*)&Ls[d * 136 + c + 8] = *(const ushort8v*)(src + 8);
  }
  __syncthreads();
#pragma unroll
  for (int w = 0; w < 4; ++w) {
    const int flat = w * 256 + tid;
    const int hb = flat & 1, lnv = (flat >> 1) & 31, dt = (flat >> 6) & 1,
              qgl = flat >> 7;
    ushort8v val = *(const ushort8v*)&Ls[(dt * 32 + lnv) * 136 + qgl * 16 + hb * 8];
    const size_t idx8 =
        (((size_t)(bh * (T / 16) + (q0 >> 4) + qgl) * 2 + dt) * 32 + lnv) * 2 + hb;
    *(ushort8v*)&vp2[idx8 * 8] = val;
  }
}

// ---------------------------------------------------------------------------
// Stats: lLog[q] = -log2( sum_k exp2(S_eff[q,k]) ). Zero LDS, zero barriers,
// all loads 1-KB coalesced from fragment-major qp2/kp2. 32x32x16 MFMA.
// Grid (T/128, B*H); wave w owns q rows q0+w*32.
// ---------------------------------------------------------------------------
__global__ __launch_bounds__(256) void attn_stats(
    const unsigned short* __restrict__ qp2, const unsigned short* __restrict__ kp2,
    float* __restrict__ lLogOut) {
  const int bh = blockIdx.y;
  const int q0 = blockIdx.x * 128;
  const int tid = threadIdx.x, wave = tid >> 6, lane = tid & 63;
  const int ln = lane & 31, half = lane >> 5;

  const int t32q = (q0 >> 5) + wave;
  f16x8 aq[4];
#pragma unroll
  for (int s = 0; s < 4; ++s)
    aq[s] = *(const f16x8*)&qp2[((((size_t)bh * (T / 32) + t32q) * 4 + s) * 64 +
                                 ln * 2 + half) * 8];

  float lacc[16];
#pragma unroll
  for (int r = 0; r < 16; ++r) lacc[r] = 0.f;

  f16x8 bkr[2][4];
#pragma unroll
  for (int nt = 0; nt < 2; ++nt)
#pragma unroll
    for (int s = 0; s < 4; ++s)
      bkr[nt][s] = *(const f16x8*)&kp2[((((size_t)bh * (T / 32) + nt) * 4 + s) * 64 +
                                        ln * 2 + half) * 8];

  for (int kt = 0; kt < T; kt += 64) {
    const int kn = (kt + 64) & (T - 1);
    f16x8 nb[2][4];
#pragma unroll
    for (int nt = 0; nt < 2; ++nt)
#pragma unroll
      for (int s = 0; s < 4; ++s)
        nb[nt][s] =
            *(const f16x8*)&kp2[((((size_t)bh * (T / 32) + (kn >> 5) + nt) * 4 + s) * 64 +
                                 ln * 2 + half) * 8];
    f32x16 S0 = {}, S1 = {};
#pragma unroll
    for (int s = 0; s < 4; ++s) {
      S0 = mfma32(aq[s], bkr[0][s], S0);
      S1 = mfma32(aq[s], bkr[1][s], S1);
    }
#pragma unroll
    for (int r = 0; r < 16; ++r) lacc[r] += exp2f(S0[r]) + exp2f(S1[r]);
#pragma unroll
    for (int nt = 0; nt < 2; ++nt)
#pragma unroll
      for (int s = 0; s < 4; ++s) bkr[nt][s] = nb[nt][s];
  }
#pragma unroll
  for (int off = 1; off < 32; off <<= 1)
#pragma unroll
    for (int r = 0; r < 16; ++r) lacc[r] += __shfl_xor(lacc[r], off, 64);
  if (ln == 0) {
#pragma unroll
    for (int t = 0; t < 4; ++t) {
      f32x4 o;
#pragma unroll
      for (int j = 0; j < 4; ++j) o[j] = -__log2f(lacc[t * 4 + j]);
      *(f32x4*)&lLogOut[(size_t)bh * T + q0 + wave * 32 + t * 8 + half * 4] = o;
    }
  }
}

// ---------------------------------------------------------------------------
// Apply: ao[d,k] = sum_q V[d,q] * exp2(S_eff[q,k] + lLog[q]).
// Grid (T/64, B*H) = 1024 blocks; 4 waves = (2 k-tiles of 32) x (2 q-halves).
// All operand loads coalesced fragment-major; P transposed C->B operand via
// 8 shfl_xor(32) + cndmask (no LDS, no barrier in the loop). lLog folded in
// the exponent. q-half partials merged once via LDS. Output fp16 t-major.
// ---------------------------------------------------------------------------
__global__ __launch_bounds__(256) void attn_apply(
    const unsigned short* __restrict__ qp2, const unsigned short* __restrict__ kp2,
    const unsigned short* __restrict__ vp2, const float* __restrict__ lLog,
    unsigned short* __restrict__ ao) {
  __shared__ float st[32 * 130];
  const int bh = blockIdx.y, b = bh >> 4, h = bh & 15;
  const int kblk = blockIdx.x * 64;
  const int tid = threadIdx.x, wave = tid >> 6, lane = tid & 63;
  const int ln = lane & 31, half = lane >> 5;
  const int kt = wave & 1, qh = wave >> 1;

  // resident K B-frags (32 k-cols)
  const int t32k = (kblk >> 5) + kt;
  f16x8 bkk[4];
#pragma unroll
  for (int s = 0; s < 4; ++s)
    bkk[s] = *(const f16x8*)&kp2[((((size_t)bh * (T / 32) + t32k) * 4 + s) * 64 +
                                  ln * 2 + half) * 8];

  f32x16 acc0 = {}, acc1 = {};
  const int qstart = qh * (T / 2);

  // prefetch iter 0
  f16x8 aqN[4], avN[2][2];
#pragma unroll
  for (int s = 0; s < 4; ++s)
    aqN[s] = *(const f16x8*)&qp2[((((size_t)bh * (T / 32) + (qstart >> 5)) * 4 + s) * 64 +
                                  ln * 2 + half) * 8];
#pragma unroll
  for (int dt = 0; dt < 2; ++dt)
#pragma unroll
    for (int f = 0; f < 2; ++f)
      avN[dt][f] = *(const f16x8*)&vp2[((((size_t)bh * (T / 16) + (qstart >> 4) + f) * 2 +
                                         dt) * 32 + ln) * 16 + half * 8];

  for (int qt = qstart; qt < qstart + T / 2; qt += 32) {
    f16x8 aq[4], av[2][2];
#pragma unroll
    for (int s = 0; s < 4; ++s) aq[s] = aqN[s];
#pragma unroll
    for (int dt = 0; dt < 2; ++dt)
#pragma unroll
      for (int f = 0; f < 2; ++f) av[dt][f] = avN[dt][f];
    // issue prefetch for next iter (wraps harmlessly on the last)
    const int qn = qt + 32 < qstart + T / 2 ? qt + 32 : qstart;
#pragma unroll
    for (int s = 0; s < 4; ++s)
      aqN[s] = *(const f16x8*)&qp2[((((size_t)bh * (T / 32) + (qn >> 5)) * 4 + s) * 64 +
                                    ln * 2 + half) * 8];
#pragma unroll
    for (int dt = 0; dt < 2; ++dt)
#pragma unroll
      for (int f = 0; f < 2; ++f)
        avN[dt][f] = *(const f16x8*)&vp2[((((size_t)bh * (T / 16) + (qn >> 4) + f) * 2 +
                                           dt) * 32 + ln) * 16 + half * 8];
    // lLog for this iter's 32 q (C-layout reg order)
    f32x4 ll[4];
#pragma unroll
    for (int t = 0; t < 4; ++t)
      ll[t] = *(const f32x4*)&lLog[(size_t)bh * T + qt + t * 8 + half * 4];
    // QK^T
    f32x16 S = {};
#pragma unroll
    for (int s = 0; s < 4; ++s) S = mfma32(aq[s], bkk[s], S);
    // P = exp2(S + lLog), packed fp16 pairs
    unsigned int w[8];
#pragma unroll
    for (int p = 0; p < 8; ++p) {
      const float e0 = exp2f(S[p * 2 + 0] + ll[p >> 1][(p & 1) * 2 + 0]);
      const float e1 = exp2f(S[p * 2 + 1] + ll[p >> 1][(p & 1) * 2 + 1]);
      w[p] = f16u(e0) | ((unsigned)f16u(e1) << 16);
    }
    // C-layout -> B-operand layout: quad-swap between wave halves
    unsigned int x[8];
#pragma unroll
    for (int p = 0; p < 8; ++p) x[p] = __shfl_xor(w[p], 32, 64);
    uint4v f0, f1;
    f0[0] = half ? x[2] : w[0];
    f0[1] = half ? x[3] : w[1];
    f0[2] = half ? w[2] : x[0];
    f0[3] = half ? w[3] : x[1];
    f1[0] = half ? x[6] : w[4];
    f1[1] = half ? x[7] : w[5];
    f1[2] = half ? w[6] : x[4];
    f1[3] = half ? w[7] : x[5];
    const f16x8 pf0 = __builtin_bit_cast(f16x8, f0);
    const f16x8 pf1 = __builtin_bit_cast(f16x8, f1);
    // PV
    acc0 = mfma32(av[0][0], pf0, acc0);
    acc0 = mfma32(av[0][1], pf1, acc0);
    acc1 = mfma32(av[1][0], pf0, acc1);
    acc1 = mfma32(av[1][1], pf1, acc1);
  }

  // merge q-half partials
  __syncthreads();
  if (qh == 1) {
#pragma unroll
    for (int i = 0; i < 16; ++i) {
      st[i * 130 + kt * 65 + lane] = acc0[i];
      st[(16 + i) * 130 + kt * 65 + lane] = acc1[i];
    }
  }
  __syncthreads();
  if (qh == 0) {
#pragma unroll
    for (int i = 0; i < 16; ++i) {
      acc0[i] += st[i * 130 + kt * 65 + lane];
      acc1[i] += st[(16 + i) * 130 + kt * 65 + lane];
    }
    const int kcol = kblk + kt * 32 + ln;
    const size_t obase = ((size_t)b * T + kcol) * E + h * DH;
#pragma unroll
    for (int dt = 0; dt < 2; ++dt) {
      const float* a = dt ? (const float*)&acc1 : (const float*)&acc0;
#pragma unroll
      for (int t = 0; t < 4; ++t) {
        uint2 wv;
        wv.x = f16u(a[t * 4 + 0]) | ((unsigned)f16u(a[t * 4 + 1]) << 16);
        wv.y = f16u(a[t * 4 + 2]) | ((unsigned)f16u(a[t * 4 + 3]) << 16);
        *(uint2*)&ao[obase + dt * 32 + t * 8 + half * 4] = wv;
      }
    }
  }
}

// ---------------------------------------------------------------------------
// Final projection, single fp16 mfma32: out = km[t]*(Wo . ao) + bo, fp32.
// Tile 64(o) x 128(t), BK=64; grid (T/128, E/64, B).
// ---------------------------------------------------------------------------
__global__ __launch_bounds__(256) void proj_final(
    const unsigned short* __restrict__ WoB, const unsigned short* __restrict__ ao,
    const float* __restrict__ bo, const float* __restrict__ kmask,
    float* __restrict__ out) {
  __shared__ unsigned short As[64 * 68], Bs[128 * 68];
  const int b = blockIdx.z, o0 = blockIdx.y * 64, t0 = blockIdx.x * 128;
  const int tid = threadIdx.x, wave = tid >> 6, lane = tid & 63;
  const int ln = lane & 31, half = lane >> 5;
  const int wn = wave * 32;
  const int ar = tid >> 2, ac = (tid & 3) * 16;
  const int br = tid >> 1, bc = (tid & 1) * 32;

  f32x16 acc0 = {}, acc1 = {};

  for (int k0 = 0; k0 < E; k0 += 64) {
    ushort8v a0 = *(const ushort8v*)&WoB[(size_t)(o0 + ar) * E + k0 + ac];
    ushort8v a1 = *(const ushort8v*)&WoB[(size_t)(o0 + ar) * E + k0 + ac + 8];
    ushort8v b0 = *(const ushort8v*)&ao[((size_t)b * T + t0 + br) * E + k0 + bc];
    ushort8v b1 = *(const ushort8v*)&ao[((size_t)b * T + t0 + br) * E + k0 + bc + 8];
    ushort8v b2 = *(const ushort8v*)&ao[((size_t)b * T + t0 + br) * E + k0 + bc + 16];
    ushort8v b3 = *(const ushort8v*)&ao[((size_t)b * T + t0 + br) * E + k0 + bc + 24];
    __syncthreads();
    *(ushort8v*)&As[ar * 68 + ac] = a0;
    *(ushort8v*)&As[ar * 68 + ac + 8] = a1;
    *(ushort8v*)&Bs[br * 68 + bc] = b0;
    *(ushort8v*)&Bs[br * 68 + bc + 8] = b1;
    *(ushort8v*)&Bs[br * 68 + bc + 16] = b2;
    *(ushort8v*)&Bs[br * 68 + bc + 24] = b3;
    __syncthreads();
#pragma unroll
    for (int s = 0; s < 4; ++s) {
      f16x8 af0 = *(const f16x8*)&As[ln * 68 + s * 16 + half * 8];
      f16x8 af1 = *(const f16x8*)&As[(32 + ln) * 68 + s * 16 + half * 8];
      f16x8 bf = *(const f16x8*)&Bs[(wn + ln) * 68 + s * 16 + half * 8];
      acc0 = mfma32(af0, bf, acc0);
      acc1 = mfma32(af1, bf, acc1);
    }
  }
  const int tcol = t0 + wn + ln;
  const float mv = kmask[b * T + tcol];
#pragma unroll
  for (int dt = 0; dt < 2; ++dt) {
    const float* a = dt ? (const float*)&acc1 : (const float*)&acc0;
#pragma unroll
    for (int t = 0; t < 4; ++t)
#pragma unroll
      for (int j = 0; j < 4; ++j) {
        const int e = o0 + dt * 32 + t * 8 + half * 4 + j;
        out[((size_t)b * E + e) * T + tcol] = a[t * 4 + j] * mv + bo[e];
      }
  }
}

extern "C" void kernel_launch(void* const* d_in, const int* in_sizes, int n_in,
                              void* d_out, int out_size, void* d_ws, size_t ws_size,
                              hipStream_t stream) {
  const float* q = (const float*)d_in[0];
  const float* k = (const float*)d_in[1];
  const float* v = (const float*)d_in[2];
  const float* qmask = (const float*)d_in[3];
  const float* kmask = (const float*)d_in[4];
  const float* vmask = (const float*)d_in[5];
  const float* Wq = (const float*)d_in[6];
  const float* bq = (const float*)d_in[7];
  const float* Wk = (const float*)d_in[8];
  const float* bk = (const float*)d_in[9];
  const float* Wv = (const float*)d_in[10];
  const float* bv = (const float*)d_in[11];
  const float* Wo = (const float*)d_in[12];
  const float* bo = (const float*)d_in[13];

  char* w = (char*)d_ws;
  const size_t WB = (size_t)E * E * sizeof(unsigned short);      // 2 MB
  const size_t TB = (size_t)B * T * E * sizeof(unsigned short);  // 8 MB
  unsigned short* WqB = (unsigned short*)(w + 0 * WB);
  unsigned short* WkB = (unsigned short*)(w + 1 * WB);
  unsigned short* WvB = (unsigned short*)(w + 2 * WB);
  unsigned short* WoB = (unsigned short*)(w + 3 * WB);
  size_t off = 4 * WB;
  unsigned short* XtQ = (unsigned short*)(w + off); off += TB;
  unsigned short* XtK = (unsigned short*)(w + off); off += TB;
  unsigned short* XtV = (unsigned short*)(w + off); off += TB;
  unsigned short* qp2 = (unsigned short*)(w + off); off += TB;
  unsigned short* kp2 = (unsigned short*)(w + off); off += TB;
  unsigned short* vp  = (unsigned short*)(w + off); off += TB;
  unsigned short* vp2 = (unsigned short*)(w + off); off += TB;
  float* lLog = (float*)(w + off); off += (size_t)B * H * T * sizeof(float);
  unsigned short* ao = XtQ;  // dead after proj_qkv

  dim3 bl(256);
  prep_weights<<<dim3((E * E) / 1024, 4), bl, 0, stream>>>(
      Wq, Wk, Wv, Wo, WqB, WkB, WvB, WoB);
  transpose_cvt<<<dim3(T / 32, E / 32, 3 * B), bl, 0, stream>>>(
      q, k, v, XtQ, XtK, XtV);
  proj_qkv<<<dim3(T / 128, 24, B), bl, 0, stream>>>(
      WqB, WkB, WvB, XtQ, XtK, XtV, bq, bk, bv, qmask, kmask, vmask, qp2, kp2, vp);
  repack_v<<<dim3(T / 128, H, B), bl, 0, stream>>>(vp, vp2);
  attn_stats<<<dim3(T / 128, B * H), bl, 0, stream>>>(qp2, kp2, lLog);
  attn_apply<<<dim3(T / 64, B * H), bl, 0, stream>>>(qp2, kp2, vp2, lLog, ao);
  proj_final<<<dim3(T / 128, E / 64, B), bl, 0, stream>>>(
      WoB, ao, bo, kmask, (float*)d_out);
}

// Round 8
// 282.445 us; speedup vs baseline: 1.4257x; 1.1366x over previous
//
#include <hip/hip_runtime.h>

#define B 2
#define E 1024
#define T 2048
#define H 16
#define DH 64

// log2(e) / sqrt(E)
#define SCALE2 0.0450842200277801f

typedef _Float16 f16x8 __attribute__((ext_vector_type(8)));
typedef float f32x4 __attribute__((ext_vector_type(4)));
typedef float f32x16 __attribute__((ext_vector_type(16)));
typedef unsigned short ushort8v __attribute__((ext_vector_type(8)));
typedef unsigned int uint4v __attribute__((ext_vector_type(4)));

__device__ __forceinline__ f32x4 mfma16(f16x8 a, f16x8 b, f32x4 c) {
  return __builtin_amdgcn_mfma_f32_16x16x32_f16(a, b, c, 0, 0, 0);
}
__device__ __forceinline__ f32x16 mfma32(f16x8 a, f16x8 b, f32x16 c) {
  return __builtin_amdgcn_mfma_f32_32x32x16_f16(a, b, c, 0, 0, 0);
}
__device__ __forceinline__ unsigned short f16u(float x) {
  _Float16 h = (_Float16)x;
  return __builtin_bit_cast(unsigned short, h);
}
// raw v_exp_f32 — safe: exponents here are in [-60, 12], far from denormals
__device__ __forceinline__ float ex2(float x) {
  return __builtin_amdgcn_exp2f(x);
}
// one-instr convert+pack (RTZ); builtin returns __fp16x2 — bit_cast to u32
__device__ __forceinline__ unsigned int pk16(float a, float b) {
  auto h = __builtin_amdgcn_cvt_pkrtz(a, b);
  return __builtin_bit_cast(unsigned int, h);
}

// ---------------------------------------------------------------------------
// Weight prep: all 4 weights -> single fp16. grid (E*E/1024, 4)
// ---------------------------------------------------------------------------
__global__ __launch_bounds__(256) void prep_weights(
    const float* __restrict__ Wq, const float* __restrict__ Wk,
    const float* __restrict__ Wv, const float* __restrict__ Wo,
    unsigned short* __restrict__ WqB, unsigned short* __restrict__ WkB,
    unsigned short* __restrict__ WvB, unsigned short* __restrict__ WoB) {
  const int which = blockIdx.y;
  const int i = (blockIdx.x * 256 + threadIdx.x) * 4;
  const float* src = which == 0 ? Wq : which == 1 ? Wk : which == 2 ? Wv : Wo;
  unsigned short* dst = which == 0 ? WqB : which == 1 ? WkB : which == 2 ? WvB : WoB;
  float4 v = *(const float4*)&src[i];
  ((unsigned int*)&dst[i])[0] = f16u(v.x) | ((unsigned)f16u(v.y) << 16);
  ((unsigned int*)&dst[i])[1] = f16u(v.z) | ((unsigned)f16u(v.w) << 16);
}

// ---------------------------------------------------------------------------
// Transpose + convert: X [B][E][T] fp32 -> Xt [B][T][E] fp16 (q,k,v in one)
// ---------------------------------------------------------------------------
__global__ __launch_bounds__(256) void transpose_cvt(
    const float* __restrict__ q, const float* __restrict__ k,
    const float* __restrict__ v, unsigned short* __restrict__ XtQ,
    unsigned short* __restrict__ XtK, unsigned short* __restrict__ XtV) {
  __shared__ float Xs[32 * 36];
  const int z = blockIdx.z, which = z >> 1, b = z & 1;
  const float* X = which == 0 ? q : which == 1 ? k : v;
  unsigned short* O = which == 0 ? XtQ : which == 1 ? XtK : XtV;
  const int e0 = blockIdx.y * 32, t0 = blockIdx.x * 32;
  const int tid = threadIdx.x;
  const int r = tid >> 3, c = (tid & 7) * 4;
  *(float4*)&Xs[r * 36 + c] = *(const float4*)&X[((size_t)b * E + e0 + r) * T + t0 + c];
  __syncthreads();
  unsigned short h[4];
#pragma unroll
  for (int j = 0; j < 4; ++j) h[j] = f16u(Xs[(c + j) * 36 + r]);
  const size_t o = ((size_t)b * T + t0 + r) * E + e0 + c;
  ((unsigned int*)&O[o])[0] = h[0] | ((unsigned)h[1] << 16);
  ((unsigned int*)&O[o])[1] = h[2] | ((unsigned)h[3] << 16);
}

// ---------------------------------------------------------------------------
// Fused q/k/v projection, fp16.
// which 0: Q_eff = qmask*SCALE2*(W x + b) -> FRAGMENT-MAJOR qp2
// which 1: K_eff = kmask*(W x + b)        -> FRAGMENT-MAJOR kp2
// which 2: vp    = vmask*(W x) + b        -> d-major [B][E][T] (repacked later)
// Fragment-major layout: [bh][T/32][4 s][32 lane][2 half][8] fp16, where the
// fragment element j maps to d = s*16 + half*8 + j and lane = t (mod 32).
// ---------------------------------------------------------------------------
__global__ __launch_bounds__(256) void proj_qkv(
    const unsigned short* __restrict__ WqB, const unsigned short* __restrict__ WkB,
    const unsigned short* __restrict__ WvB, const unsigned short* __restrict__ XtQ,
    const unsigned short* __restrict__ XtK, const unsigned short* __restrict__ XtV,
    const float* __restrict__ bq, const float* __restrict__ bk,
    const float* __restrict__ bv, const float* __restrict__ qmask,
    const float* __restrict__ kmask, const float* __restrict__ vmask,
    unsigned short* __restrict__ qp2, unsigned short* __restrict__ kp2,
    unsigned short* __restrict__ vp) {
  __shared__ unsigned short Ah[128 * 72], Bs[128 * 72];
  const int b = blockIdx.z, my = blockIdx.y;
  const int which = my >> 3, o0 = (my & 7) * 128, t0 = blockIdx.x * 128;
  const unsigned short* W = which == 0 ? WqB : which == 1 ? WkB : WvB;
  const unsigned short* Xt = which == 0 ? XtQ : which == 1 ? XtK : XtV;
  const float* bias = which == 0 ? bq : which == 1 ? bk : bv;
  const float* mask = which == 0 ? qmask : which == 1 ? kmask : vmask;

  const int tid = threadIdx.x, wave = tid >> 6, lane = tid & 63;
  const int lg = lane & 15, quad = lane >> 4;
  const int wm = (wave & 1) * 64, wn = (wave >> 1) * 64;
  const int sr = tid >> 3, sc = (tid & 7) * 8;

  f32x4 acc[4][4];
#pragma unroll
  for (int i = 0; i < 4; ++i)
#pragma unroll
    for (int j = 0; j < 4; ++j) acc[i][j] = (f32x4){0.f, 0.f, 0.f, 0.f};

  for (int k0 = 0; k0 < E; k0 += 64) {
    ushort8v ra[4], rb[4];
#pragma unroll
    for (int p = 0; p < 4; ++p) {
      ra[p] = *(const ushort8v*)&W[(size_t)(o0 + p * 32 + sr) * E + k0 + sc];
      rb[p] = *(const ushort8v*)&Xt[((size_t)b * T + t0 + p * 32 + sr) * E + k0 + sc];
    }
    __syncthreads();
#pragma unroll
    for (int p = 0; p < 4; ++p) {
      *(ushort8v*)&Ah[(p * 32 + sr) * 72 + sc] = ra[p];
      *(ushort8v*)&Bs[(p * 32 + sr) * 72 + sc] = rb[p];
    }
    __syncthreads();
    f16x8 af[4][2];
#pragma unroll
    for (int mt = 0; mt < 4; ++mt) {
      af[mt][0] = *(const f16x8*)&Ah[(wm + mt * 16 + lg) * 72 + quad * 8];
      af[mt][1] = *(const f16x8*)&Ah[(wm + mt * 16 + lg) * 72 + 32 + quad * 8];
    }
#pragma unroll
    for (int nt = 0; nt < 4; ++nt) {
      f16x8 b0 = *(const f16x8*)&Bs[(wn + nt * 16 + lg) * 72 + quad * 8];
      f16x8 b1 = *(const f16x8*)&Bs[(wn + nt * 16 + lg) * 72 + 32 + quad * 8];
#pragma unroll
      for (int mt = 0; mt < 4; ++mt) {
        f32x4 c = acc[mt][nt];
        c = mfma16(af[mt][0], b0, c);
        c = mfma16(af[mt][1], b1, c);
        acc[mt][nt] = c;
      }
    }
  }
#pragma unroll
  for (int nt = 0; nt < 4; ++nt) {
    const int tcol = t0 + wn + nt * 16 + lg;
    const float mv = mask[b * T + tcol];
#pragma unroll
    for (int mt = 0; mt < 4; ++mt) {
      const int oF = o0 + wm + mt * 16 + quad * 4;
      float v4[4];
      if (which == 0) {
        const float s = mv * SCALE2;
#pragma unroll
        for (int r = 0; r < 4; ++r) v4[r] = (acc[mt][nt][r] + bias[oF + r]) * s;
      } else if (which == 1) {
#pragma unroll
        for (int r = 0; r < 4; ++r) v4[r] = (acc[mt][nt][r] + bias[oF + r]) * mv;
      } else {
#pragma unroll
        for (int r = 0; r < 4; ++r) v4[r] = acc[mt][nt][r] * mv + bias[oF + r];
      }
      if (which <= 1) {
        unsigned short* O = which == 0 ? qp2 : kp2;
        const int head = (o0 + wm) >> 6;
        const int bh2 = b * H + head;
        const size_t idx8 =
            (((size_t)(bh2 * (T / 32) + (tcol >> 5)) * 4 + mt) * 32 + (tcol & 31)) * 2 +
            (quad >> 1);
        unsigned int* dst = (unsigned int*)(O + idx8 * 8 + (quad & 1) * 4);
        dst[0] = f16u(v4[0]) | ((unsigned)f16u(v4[1]) << 16);
        dst[1] = f16u(v4[2]) | ((unsigned)f16u(v4[3]) << 16);
      } else {
#pragma unroll
        for (int r = 0; r < 4; ++r)
          vp[((size_t)b * E + oF + r) * T + tcol] = f16u(v4[r]);
      }
    }
  }
}

// ---------------------------------------------------------------------------
// Repack V: vp d-major [B][E][T] -> vp2 A-fragment-major
// [bh][T/16][2 dt][32 lane(d)][2 half][8] fp16 (element j -> q = half*8+j).
// grid (T/128, H, B), block 256.
// ---------------------------------------------------------------------------
__global__ __launch_bounds__(256) void repack_v(
    const unsigned short* __restrict__ vp, unsigned short* __restrict__ vp2) {
  __shared__ unsigned short Ls[64 * 136];
  const int q0 = blockIdx.x * 128, hh = blockIdx.y, b = blockIdx.z;
  const int bh = b * H + hh;
  const int tid = threadIdx.x;
  // stage 64 d x 128 q, coalesced
#pragma unroll
  for (int w = 0; w < 2; ++w) {
    const int d = w * 32 + (tid >> 3);
    const int c = (tid & 7) * 16;
    const unsigned short* src = vp + ((size_t)b * E + hh * DH + d) * T + q0 + c;
    *(ushort8v*)&Ls[d * 136 + c] = *(const ushort8v*)src;
    *(ushort8v*)&Ls[d * 136 + c + 8] = *(const ushort8v*)(src + 8);
  }
  __syncthreads();
#pragma unroll
  for (int w = 0; w < 4; ++w) {
    const int flat = w * 256 + tid;
    const int hb = flat & 1, lnv = (flat >> 1) & 31, dt = (flat >> 6) & 1,
              qgl = flat >> 7;
    ushort8v val = *(const ushort8v*)&Ls[(dt * 32 + lnv) * 136 + qgl * 16 + hb * 8];
    const size_t idx8 =
        (((size_t)(bh * (T / 16) + (q0 >> 4) + qgl) * 2 + dt) * 32 + lnv) * 2 + hb;
    *(ushort8v*)&vp2[idx8 * 8] = val;
  }
}

// ---------------------------------------------------------------------------
// Stats: lLog[q] = -log2( sum_k exp2(S_eff[q,k]) ). Zero LDS, zero barriers,
// all loads 1-KB coalesced from fragment-major qp2/kp2. 32x32x16 MFMA.
// Grid (T/128, B*H); wave w owns q rows q0+w*32.
// ---------------------------------------------------------------------------
__global__ __launch_bounds__(256) void attn_stats(
    const unsigned short* __restrict__ qp2, const unsigned short* __restrict__ kp2,
    float* __restrict__ lLogOut) {
  const int bh = blockIdx.y;
  const int q0 = blockIdx.x * 128;
  const int tid = threadIdx.x, wave = tid >> 6, lane = tid & 63;
  const int ln = lane & 31, half = lane >> 5;

  const int t32q = (q0 >> 5) + wave;
  f16x8 aq[4];
#pragma unroll
  for (int s = 0; s < 4; ++s)
    aq[s] = *(const f16x8*)&qp2[((((size_t)bh * (T / 32) + t32q) * 4 + s) * 64 +
                                 ln * 2 + half) * 8];

  float lacc[16];
#pragma unroll
  for (int r = 0; r < 16; ++r) lacc[r] = 0.f;

  f16x8 bkr[2][4];
#pragma unroll
  for (int nt = 0; nt < 2; ++nt)
#pragma unroll
    for (int s = 0; s < 4; ++s)
      bkr[nt][s] = *(const f16x8*)&kp2[((((size_t)bh * (T / 32) + nt) * 4 + s) * 64 +
                                        ln * 2 + half) * 8];

  for (int kt = 0; kt < T; kt += 64) {
    const int kn = (kt + 64) & (T - 1);
    f16x8 nb[2][4];
#pragma unroll
    for (int nt = 0; nt < 2; ++nt)
#pragma unroll
      for (int s = 0; s < 4; ++s)
        nb[nt][s] =
            *(const f16x8*)&kp2[((((size_t)bh * (T / 32) + (kn >> 5) + nt) * 4 + s) * 64 +
                                 ln * 2 + half) * 8];
    f32x16 S0 = {}, S1 = {};
#pragma unroll
    for (int s = 0; s < 4; ++s) {
      S0 = mfma32(aq[s], bkr[0][s], S0);
      S1 = mfma32(aq[s], bkr[1][s], S1);
    }
#pragma unroll
    for (int r = 0; r < 16; ++r) lacc[r] += ex2(S0[r]) + ex2(S1[r]);
#pragma unroll
    for (int nt = 0; nt < 2; ++nt)
#pragma unroll
      for (int s = 0; s < 4; ++s) bkr[nt][s] = nb[nt][s];
  }
#pragma unroll
  for (int off = 1; off < 32; off <<= 1)
#pragma unroll
    for (int r = 0; r < 16; ++r) lacc[r] += __shfl_xor(lacc[r], off, 64);
  if (ln == 0) {
#pragma unroll
    for (int t = 0; t < 4; ++t) {
      f32x4 o;
#pragma unroll
      for (int j = 0; j < 4; ++j) o[j] = -__builtin_amdgcn_logf(lacc[t * 4 + j]);
      *(f32x4*)&lLogOut[(size_t)bh * T + q0 + wave * 32 + t * 8 + half * 4] = o;
    }
  }
}

// ---------------------------------------------------------------------------
// Apply: ao[d,k] = sum_q V[d,q] * exp2(S_eff[q,k] + lLog[q]).
// Grid (T/64, B*H) = 1024 blocks; 4 waves = (2 k-tiles of 32) x (2 q-halves).
// All operand loads coalesced fragment-major; P transposed C->B operand via
// 8 shfl_xor(32) + cndmask (no LDS, no barrier in the loop). lLog folded in
// the exponent. q-half partials merged once via LDS. Output fp16 t-major.
// ---------------------------------------------------------------------------
__global__ __launch_bounds__(256) void attn_apply(
    const unsigned short* __restrict__ qp2, const unsigned short* __restrict__ kp2,
    const unsigned short* __restrict__ vp2, const float* __restrict__ lLog,
    unsigned short* __restrict__ ao) {
  __shared__ float st[32 * 130];
  const int bh = blockIdx.y, b = bh >> 4, h = bh & 15;
  const int kblk = blockIdx.x * 64;
  const int tid = threadIdx.x, wave = tid >> 6, lane = tid & 63;
  const int ln = lane & 31, half = lane >> 5;
  const int kt = wave & 1, qh = wave >> 1;

  // resident K B-frags (32 k-cols)
  const int t32k = (kblk >> 5) + kt;
  f16x8 bkk[4];
#pragma unroll
  for (int s = 0; s < 4; ++s)
    bkk[s] = *(const f16x8*)&kp2[((((size_t)bh * (T / 32) + t32k) * 4 + s) * 64 +
                                  ln * 2 + half) * 8];

  f32x16 acc0 = {}, acc1 = {};
  const int qstart = qh * (T / 2);

  // prefetch iter 0
  f16x8 aqN[4], avN[2][2];
#pragma unroll
  for (int s = 0; s < 4; ++s)
    aqN[s] = *(const f16x8*)&qp2[((((size_t)bh * (T / 32) + (qstart >> 5)) * 4 + s) * 64 +
                                  ln * 2 + half) * 8];
#pragma unroll
  for (int dt = 0; dt < 2; ++dt)
#pragma unroll
    for (int f = 0; f < 2; ++f)
      avN[dt][f] = *(const f16x8*)&vp2[((((size_t)bh * (T / 16) + (qstart >> 4) + f) * 2 +
                                         dt) * 32 + ln) * 16 + half * 8];

  for (int qt = qstart; qt < qstart + T / 2; qt += 32) {
    f16x8 aq[4], av[2][2];
#pragma unroll
    for (int s = 0; s < 4; ++s) aq[s] = aqN[s];
#pragma unroll
    for (int dt = 0; dt < 2; ++dt)
#pragma unroll
      for (int f = 0; f < 2; ++f) av[dt][f] = avN[dt][f];
    // issue prefetch for next iter (wraps harmlessly on the last)
    const int qn = qt + 32 < qstart + T / 2 ? qt + 32 : qstart;
#pragma unroll
    for (int s = 0; s < 4; ++s)
      aqN[s] = *(const f16x8*)&qp2[((((size_t)bh * (T / 32) + (qn >> 5)) * 4 + s) * 64 +
                                    ln * 2 + half) * 8];
#pragma unroll
    for (int dt = 0; dt < 2; ++dt)
#pragma unroll
      for (int f = 0; f < 2; ++f)
        avN[dt][f] = *(const f16x8*)&vp2[((((size_t)bh * (T / 16) + (qn >> 4) + f) * 2 +
                                           dt) * 32 + ln) * 16 + half * 8];
    // lLog for this iter's 32 q (C-layout reg order)
    f32x4 ll[4];
#pragma unroll
    for (int t = 0; t < 4; ++t)
      ll[t] = *(const f32x4*)&lLog[(size_t)bh * T + qt + t * 8 + half * 4];
    // QK^T
    f32x16 S = {};
#pragma unroll
    for (int s = 0; s < 4; ++s) S = mfma32(aq[s], bkk[s], S);
    // P = exp2(S + lLog), packed fp16 pairs (raw v_exp + pkrtz)
    unsigned int w[8];
#pragma unroll
    for (int p = 0; p < 8; ++p) {
      const float e0 = ex2(S[p * 2 + 0] + ll[p >> 1][(p & 1) * 2 + 0]);
      const float e1 = ex2(S[p * 2 + 1] + ll[p >> 1][(p & 1) * 2 + 1]);
      w[p] = pk16(e0, e1);
    }
    // C-layout -> B-operand layout: quad-swap between wave halves
    unsigned int x[8];
#pragma unroll
    for (int p = 0; p < 8; ++p) x[p] = __shfl_xor(w[p], 32, 64);
    uint4v f0, f1;
    f0[0] = half ? x[2] : w[0];
    f0[1] = half ? x[3] : w[1];
    f0[2] = half ? w[2] : x[0];
    f0[3] = half ? w[3] : x[1];
    f1[0] = half ? x[6] : w[4];
    f1[1] = half ? x[7] : w[5];
    f1[2] = half ? w[6] : x[4];
    f1[3] = half ? w[7] : x[5];
    const f16x8 pf0 = __builtin_bit_cast(f16x8, f0);
    const f16x8 pf1 = __builtin_bit_cast(f16x8, f1);
    // PV
    acc0 = mfma32(av[0][0], pf0, acc0);
    acc0 = mfma32(av[0][1], pf1, acc0);
    acc1 = mfma32(av[1][0], pf0, acc1);
    acc1 = mfma32(av[1][1], pf1, acc1);
  }

  // merge q-half partials
  __syncthreads();
  if (qh == 1) {
#pragma unroll
    for (int i = 0; i < 16; ++i) {
      st[i * 130 + kt * 65 + lane] = acc0[i];
      st[(16 + i) * 130 + kt * 65 + lane] = acc1[i];
    }
  }
  __syncthreads();
  if (qh == 0) {
#pragma unroll
    for (int i = 0; i < 16; ++i) {
      acc0[i] += st[i * 130 + kt * 65 + lane];
      acc1[i] += st[(16 + i) * 130 + kt * 65 + lane];
    }
    const int kcol = kblk + kt * 32 + ln;
    const size_t obase = ((size_t)b * T + kcol) * E + h * DH;
#pragma unroll
    for (int dt = 0; dt < 2; ++dt) {
      const float* a = dt ? (const float*)&acc1 : (const float*)&acc0;
#pragma unroll
      for (int t = 0; t < 4; ++t) {
        uint2 wv;
        wv.x = f16u(a[t * 4 + 0]) | ((unsigned)f16u(a[t * 4 + 1]) << 16);
        wv.y = f16u(a[t * 4 + 2]) | ((unsigned)f16u(a[t * 4 + 3]) << 16);
        *(uint2*)&ao[obase + dt * 32 + t * 8 + half * 4] = wv;
      }
    }
  }
}

// ---------------------------------------------------------------------------
// Final projection, single fp16 mfma32: out = km[t]*(Wo . ao) + bo, fp32.
// Tile 64(o) x 128(t), BK=64; grid (T/128, E/64, B).
// ---------------------------------------------------------------------------
__global__ __launch_bounds__(256) void proj_final(
    const unsigned short* __restrict__ WoB, const unsigned short* __restrict__ ao,
    const float* __restrict__ bo, const float* __restrict__ kmask,
    float* __restrict__ out) {
  __shared__ unsigned short As[64 * 68], Bs[128 * 68];
  const int b = blockIdx.z, o0 = blockIdx.y * 64, t0 = blockIdx.x * 128;
  const int tid = threadIdx.x, wave = tid >> 6, lane = tid & 63;
  const int ln = lane & 31, half = lane >> 5;
  const int wn = wave * 32;
  const int ar = tid >> 2, ac = (tid & 3) * 16;
  const int br = tid >> 1, bc = (tid & 1) * 32;

  f32x16 acc0 = {}, acc1 = {};

  for (int k0 = 0; k0 < E; k0 += 64) {
    ushort8v a0 = *(const ushort8v*)&WoB[(size_t)(o0 + ar) * E + k0 + ac];
    ushort8v a1 = *(const ushort8v*)&WoB[(size_t)(o0 + ar) * E + k0 + ac + 8];
    ushort8v b0 = *(const ushort8v*)&ao[((size_t)b * T + t0 + br) * E + k0 + bc];
    ushort8v b1 = *(const ushort8v*)&ao[((size_t)b * T + t0 + br) * E + k0 + bc + 8];
    ushort8v b2 = *(const ushort8v*)&ao[((size_t)b * T + t0 + br) * E + k0 + bc + 16];
    ushort8v b3 = *(const ushort8v*)&ao[((size_t)b * T + t0 + br) * E + k0 + bc + 24];
    __syncthreads();
    *(ushort8v*)&As[ar * 68 + ac] = a0;
    *(ushort8v*)&As[ar * 68 + ac + 8] = a1;
    *(ushort8v*)&Bs[br * 68 + bc] = b0;
    *(ushort8v*)&Bs[br * 68 + bc + 8] = b1;
    *(ushort8v*)&Bs[br * 68 + bc + 16] = b2;
    *(ushort8v*)&Bs[br * 68 + bc + 24] = b3;
    __syncthreads();
#pragma unroll
    for (int s = 0; s < 4; ++s) {
      f16x8 af0 = *(const f16x8*)&As[ln * 68 + s * 16 + half * 8];
      f16x8 af1 = *(const f16x8*)&As[(32 + ln) * 68 + s * 16 + half * 8];
      f16x8 bf = *(const f16x8*)&Bs[(wn + ln) * 68 + s * 16 + half * 8];
      acc0 = mfma32(af0, bf, acc0);
      acc1 = mfma32(af1, bf, acc1);
    }
  }
  const int tcol = t0 + wn + ln;
  const float mv = kmask[b * T + tcol];
#pragma unroll
  for (int dt = 0; dt < 2; ++dt) {
    const float* a = dt ? (const float*)&acc1 : (const float*)&acc0;
#pragma unroll
    for (int t = 0; t < 4; ++t)
#pragma unroll
      for (int j = 0; j < 4; ++j) {
        const int e = o0 + dt * 32 + t * 8 + half * 4 + j;
        out[((size_t)b * E + e) * T + tcol] = a[t * 4 + j] * mv + bo[e];
      }
  }
}

extern "C" void kernel_launch(void* const* d_in, const int* in_sizes, int n_in,
                              void* d_out, int out_size, void* d_ws, size_t ws_size,
                              hipStream_t stream) {
  const float* q = (const float*)d_in[0];
  const float* k = (const float*)d_in[1];
  const float* v = (const float*)d_in[2];
  const float* qmask = (const float*)d_in[3];
  const float* kmask = (const float*)d_in[4];
  const float* vmask = (const float*)d_in[5];
  const float* Wq = (const float*)d_in[6];
  const float* bq = (const float*)d_in[7];
  const float* Wk = (const float*)d_in[8];
  const float* bk = (const float*)d_in[9];
  const float* Wv = (const float*)d_in[10];
  const float* bv = (const float*)d_in[11];
  const float* Wo = (const float*)d_in[12];
  const float* bo = (const float*)d_in[13];

  char* w = (char*)d_ws;
  const size_t WB = (size_t)E * E * sizeof(unsigned short);      // 2 MB
  const size_t TB = (size_t)B * T * E * sizeof(unsigned short);  // 8 MB
  unsigned short* WqB = (unsigned short*)(w + 0 * WB);
  unsigned short* WkB = (unsigned short*)(w + 1 * WB);
  unsigned short* WvB = (unsigned short*)(w + 2 * WB);
  unsigned short* WoB = (unsigned short*)(w + 3 * WB);
  size_t off = 4 * WB;
  unsigned short* XtQ = (unsigned short*)(w + off); off += TB;
  unsigned short* XtK = (unsigned short*)(w + off); off += TB;
  unsigned short* XtV = (unsigned short*)(w + off); off += TB;
  unsigned short* qp2 = (unsigned short*)(w + off); off += TB;
  unsigned short* kp2 = (unsigned short*)(w + off); off += TB;
  unsigned short* vp  = (unsigned short*)(w + off); off += TB;
  unsigned short* vp2 = (unsigned short*)(w + off); off += TB;
  float* lLog = (float*)(w + off); off += (size_t)B * H * T * sizeof(float);
  unsigned short* ao = XtQ;  // dead after proj_qkv

  dim3 bl(256);
  prep_weights<<<dim3((E * E) / 1024, 4), bl, 0, stream>>>(
      Wq, Wk, Wv, Wo, WqB, WkB, WvB, WoB);
  transpose_cvt<<<dim3(T / 32, E / 32, 3 * B), bl, 0, stream>>>(
      q, k, v, XtQ, XtK, XtV);
  proj_qkv<<<dim3(T / 128, 24, B), bl, 0, stream>>>(
      WqB, WkB, WvB, XtQ, XtK, XtV, bq, bk, bv, qmask, kmask, vmask, qp2, kp2, vp);
  repack_v<<<dim3(T / 128, H, B), bl, 0, stream>>>(vp, vp2);
  attn_stats<<<dim3(T / 128, B * H), bl, 0, stream>>>(qp2, kp2, lLog);
  attn_apply<<<dim3(T / 64, B * H), bl, 0, stream>>>(qp2, kp2, vp2, lLog, ao);
  proj_final<<<dim3(T / 128, E / 64, B), bl, 0, stream>>>(
      WoB, ao, bo, kmask, (float*)d_out);
}